// Round 1
// baseline (79.470 us; speedup 1.0000x reference)
//
#include <hip/hip_runtime.h>
#include <hip/hip_fp16.h>

// DRN layer — economized-cubic / moment factorization, 8-byte LDS n-plane.
//
//  x = w*d2, |x| <= h = 0.1*(63/64)^2 = 0.0969.
//  exp(-x) ~= a0 - x + a2*x^2 - x^3/6   (Chebyshev-economized Taylor-4:
//      x^4 ~= h^2 x^2 - h^4/8 on [-h,h]; a2 = 1/2 + h^2/24, a0 = 1 - h^4/192)
//  Pw = a0*m0 * [1 + (-w)(N1 + (-w)(N2 + (-w)N3))],
//     N1 = M1/m0, N2 = a2*M2/m0, N3 = (1/6)*M3/m0,  M_n = sum_m d2^n P[i,k,m].
//  a0*m0 is (j,l)-independent -> cancels in softmax (a0 dropped entirely).
//  M_n from raw moments mom_0..mom_6 via binomial in z = -s_l.
//  poly in [0.905,1.10] -> product over 64 k within 2^+-9.3: ONE log2 per j,
//  exp2-softmax safe with NO max-shift.
//
// R5 (this round): occupancy attack. Previous config (grid 512, 4 j/wave,
// 2 blocks/CU = 4 waves/SIMD) measured ~34 us vs a ~5-7 us VALU-issue floor
// -> latency-bound at 50% occupancy. Changes:
//   * grid = 1024 (i = bid>>2, jq = bid&3), wave owns 2 j  -> 4 blocks/CU,
//     8 waves/SIMD (needs <=64 VGPR: __launch_bounds__(512,8); LDS 32KB*4 = 128KB).
//   * phase 1 -> phase 2 fused WITHOUT __syncthreads: wave wv produces moments
//     for exactly k in [wv*8, wv*8+8) and consumes only those in phase 2 ->
//     broadcast the 7 moments via __shfl from lane kk*8 (v_readlane), lds_mom
//     buffer + first barrier + divergent mc==0 writes all deleted.
// Main loop per (k,lane): ONE conflict-free ds_read_b64 (n1 fp32 | n2,n3 fp16x2).

#define NUP 64
#define NLOW 64
#define QUP 64
#define QLOW 64

__global__ __launch_bounds__(512, 8)
void drn_kernel(const float* __restrict__ P,
                const float* __restrict__ weight,
                const float* __restrict__ bias_abs,
                const float* __restrict__ bias_q,
                const float* __restrict__ lambda_abs,
                const float* __restrict__ lambda_q,
                float* __restrict__ out)
{
    __shared__ float2 lds_n[NLOW * QUP];         // (n1 | n2,n3 fp16) per (k,l) 32 KB

    const int i    = blockIdx.x >> 2;
    const int jq   = blockIdx.x & 3;
    const int tid  = threadIdx.x;
    const int lane = tid & 63;
    const int wv   = __builtin_amdgcn_readfirstlane(tid >> 6);   // 0..7, uniform

    // ---------------- phase 1: raw moments mom_0..6 (wave-local k range) -------
    // lane = (kk, mc): k = wv*8+kk ; m in [mc*8, mc*8+8)
    float t0 = 0.f, t1 = 0.f, t2 = 0.f, t3 = 0.f, t4 = 0.f, t5 = 0.f, t6 = 0.f;
    {
        const int kk = lane >> 3;
        const int mc = lane & 7;
        const int k  = wv * 8 + kk;
        const float* Pr = P + ((size_t)i * NLOW + k) * QLOW + mc * 8;
        const float4 pa = *reinterpret_cast<const float4*>(Pr);
        const float4 pb = *reinterpret_cast<const float4*>(Pr + 4);

        const float s0 = (float)(mc * 8) * 0.015625f;
#define ACCM(PV, S) { float f = (PV); const float s_ = (S); \
        t0 += f; f *= s_; t1 += f; f *= s_; t2 += f; f *= s_; t3 += f; \
        f *= s_; t4 += f; f *= s_; t5 += f; f *= s_; t6 += f; }
        ACCM(pa.x, s0);
        ACCM(pa.y, s0 + 0.015625f);
        ACCM(pa.z, s0 + 0.03125f);
        ACCM(pa.w, s0 + 0.046875f);
        ACCM(pb.x, s0 + 0.0625f);
        ACCM(pb.y, s0 + 0.078125f);
        ACCM(pb.z, s0 + 0.09375f);
        ACCM(pb.w, s0 + 0.109375f);
#undef ACCM
#define RED7(OFF) { t0 += __shfl_xor(t0, OFF, 64); t1 += __shfl_xor(t1, OFF, 64); \
        t2 += __shfl_xor(t2, OFF, 64); t3 += __shfl_xor(t3, OFF, 64); \
        t4 += __shfl_xor(t4, OFF, 64); t5 += __shfl_xor(t5, OFF, 64); \
        t6 += __shfl_xor(t6, OFF, 64); }
        RED7(1) RED7(2) RED7(4)
#undef RED7
        // every lane of 8-lane group kk now holds the full moments of k=wv*8+kk
    }

    // ---------------- phase 2 (fused, no barrier): 8-byte n(k,l) plane ---------
    const float s1l = (float)lane * 0.015625f;
    {
        const float A2 = 0.50039123f;            // 1/2 + h^2/24, h = 0.1*(63/64)^2
        const float C6 = 1.0f / 6.0f;
        const float z  = -s1l;
        const float z2 = z * z, z3 = z2 * z, z4 = z2 * z2, z5 = z4 * z, z6 = z4 * z2;
        // M1 coeffs on mom0..2 ; M2 on mom0..4 ; M3 on mom0..6
        const float b10 = z2,        b11 = 2.f * z;
        const float b20 = z4,        b21 = 4.f * z3, b22 = 6.f * z2, b23 = 4.f * z;
        const float b30 = z6,        b31 = 6.f * z5, b32 = 15.f * z4,
                    b33 = 20.f * z3, b34 = 15.f * z2, b35 = 6.f * z;

#pragma unroll
        for (int kk = 0; kk < 8; ++kk) {
            const int k = wv * 8 + kk;
            // wave-local broadcast of this k's moments (compile-time src lane
            // -> v_readlane_b32, scalar-friendly, replaces lds_mom round-trip)
            const float m0 = __shfl(t0, kk * 8, 64);
            const float m1 = __shfl(t1, kk * 8, 64);
            const float m2 = __shfl(t2, kk * 8, 64);
            const float m3 = __shfl(t3, kk * 8, 64);
            const float m4 = __shfl(t4, kk * 8, 64);
            const float m5 = __shfl(t5, kk * 8, 64);
            const float m6 = __shfl(t6, kk * 8, 64);

            const float inv = 1.0f / m0;         // 1/m0
            const float M1 = fmaf(b10, m0, fmaf(b11, m1, m2));
            const float M2 = fmaf(b20, m0, fmaf(b21, m1, fmaf(b22, m2,
                             fmaf(b23, m3, m4))));
            const float M3 = fmaf(b30, m0, fmaf(b31, m1, fmaf(b32, m2,
                             fmaf(b33, m3, fmaf(b34, m4, fmaf(b35, m5, m6))))));

            const float n1 = M1 * inv;
            const float n2 = A2 * M2 * inv;
            const float n3 = C6 * M3 * inv;

            union { __half2 h; float f; } pk;
            pk.h = __floats2half2_rn(n2, n3);
            float2 e; e.x = n1; e.y = pk.f;
            lds_n[k * QUP + lane] = e;
        }
    }
    __syncthreads();   // cross-wave: main loop reads all 64 k

    // ---------------- main loop: 64 k (rolled by 8), this wave's 2 j's ---------
    // Weight rows are wave-uniform -> scalar-friendly addressing.
    const float* __restrict__ w0r = weight + (size_t)(jq * 16 + wv * 2 + 0) * NLOW;
    const float* __restrict__ w1r = weight + (size_t)(jq * 16 + wv * 2 + 1) * NLOW;

    float pr0 = 1.f, pr1 = 1.f;
    for (int k8 = 0; k8 < 8; ++k8) {
        float w0[8], w1[8];
#pragma unroll
        for (int kk = 0; kk < 8; ++kk) {
            w0[kk] = w0r[k8 * 8 + kk];
            w1[kk] = w1r[k8 * 8 + kk];
        }
#pragma unroll
        for (int kk = 0; kk < 8; ++kk) {
            const float2 v = lds_n[(k8 * 8 + kk) * QUP + lane];
            union { float f; __half2 h; } pk; pk.f = v.y;
            const float2 n23 = __half22float2(pk.h);   // (n2, n3)
#define STEPJ(W, PR) { const float w_ = (W); \
            float t = fmaf(-w_, n23.y, n23.x); \
            t = fmaf(-w_, t, v.x); \
            PR *= fmaf(-w_, t, 1.0f); }
            STEPJ(w0[kk], pr0)
            STEPJ(w1[kk], pr1)
#undef STEPJ
        }
    }

    // ---------------- epilogue: exponent_B + base-2 softmax (no max-shift) -----
    const float LOG2E = 1.4426950408889634f;
    auto finish = [&](float prv, int jj) {
        const int j = jq * 16 + wv * 2 + jj;
        const float dq = s1l - lambda_q[j];
        float y = __log2f(prv);                     // |y| <= ~9.3
        y = fmaf(-bias_q[j] * LOG2E, dq * dq, y);
        y = fmaf(-bias_abs[j] * LOG2E, fabsf(s1l - lambda_abs[j]), y);
        const float e = exp2f(y);                   // fp32-safe without max-shift
        float s = e;
#pragma unroll
        for (int off = 32; off >= 1; off >>= 1)
            s += __shfl_xor(s, off, 64);
        out[((size_t)i * NUP + j) * QUP + lane] = e / s;
    };
    finish(pr0, 0);
    finish(pr1, 1);
}

extern "C" void kernel_launch(void* const* d_in, const int* in_sizes, int n_in,
                              void* d_out, int out_size, void* d_ws, size_t ws_size,
                              hipStream_t stream) {
    const float* P          = (const float*)d_in[0];
    const float* weight     = (const float*)d_in[1];
    const float* bias_abs   = (const float*)d_in[2];
    const float* bias_q     = (const float*)d_in[3];
    const float* lambda_abs = (const float*)d_in[4];
    const float* lambda_q   = (const float*)d_in[5];
    (void)in_sizes; (void)n_in; (void)out_size; (void)d_ws; (void)ws_size;

    drn_kernel<<<dim3(1024), dim3(512), 0, stream>>>(
        P, weight, bias_abs, bias_q, lambda_abs, lambda_q, (float*)d_out);
}